// Round 14
// baseline (211.301 us; speedup 1.0000x reference)
//
#include <hip/hip_runtime.h>
#include <hip/hip_fp16.h>
#include <stdint.h>

#define NPTS (96*96*96)          // 884736
#define NP5  (NPTS*5)            // 4423680 entries (point,vertex)

// Dense lattice grid (interval arithmetic from fixed domain: z,y,x in [0,95],
// image in [0,1); incl. rank-adjust, r-offset, blur padding, +/-2 margin):
//   q0 in [-3,25], q1 in [-14,14], q2 in [-16,8], q3 in [-17,3]
#define GD1 33
#define GD2 29
#define GD3 25
#define GO0 5
#define GO1 16
#define GO2 18
#define GO3 19
#define GS3 5
#define GS2 (GD3*GS3)      // 125
#define GS1 (GD2*GS2)      // 3625
#define GS0 (GD1*GS1)      // 119625
#define GCELLS (31*GS0)    // 3708375
#define GCELLS1 (GCELLS+1) // + trash cell for (never-expected) OOB
#define GSSUM (GS0+GS1+GS2+GS3)  // 123380

#define LHS 2048           // block-local LDS hash slots (1280 entries -> load <=0.625)

struct LatPt { int cell[5]; float w[5]; };

// Per-cell value record: 12B = { q01:half2, q23:half2, w4:float }.
// Numerators fp16 (rounded per pass), denominator fp32 (exact). int3 access.

// Shared per-point lattice math macro producing rank[5], rem0i[4], b[]
#define LATTICE_MATH(n)                                                        \
  int x = n % 96, y = (n / 96) % 96, z = n / (96 * 96);                        \
  float cf[4];                                                                 \
  cf[0] = ((float)z / 5.0f) * 2.8867513459481287f;                             \
  cf[1] = ((float)y / 5.0f) * 1.6666666666666667f;                             \
  cf[2] = ((float)x / 5.0f) * 1.1785113019775793f;                             \
  cf[3] = (imgv / 0.25f) * 0.9128709291752769f;                                \
  float elev[5];                                                               \
  float sm = 0.f;                                                              \
  _Pragma("unroll")                                                            \
  for (int i = 4; i >= 1; --i){ float c = cf[i-1]; elev[i] = sm - (float)i * c; sm += c; } \
  elev[0] = sm;                                                                \
  float rem0[5]; float sumrd_f = 0.f;                                          \
  _Pragma("unroll")                                                            \
  for (int i = 0; i < 5; i++){ float rd = rintf(elev[i] / 5.0f); rem0[i] = rd * 5.0f; sumrd_f += rd; } \
  int sum_rd = (int)sumrd_f;                                                   \
  float diff[5];                                                               \
  _Pragma("unroll")                                                            \
  for (int i = 0; i < 5; i++) diff[i] = elev[i] - rem0[i];                     \
  int rank[5];                                                                 \
  _Pragma("unroll")                                                            \
  for (int i = 0; i < 5; i++){                                                 \
    int r = 0;                                                                 \
    _Pragma("unroll")                                                          \
    for (int j = 0; j < 5; j++){                                               \
      r += (diff[j] > diff[i] || (diff[j] == diff[i] && j < i)) ? 1 : 0;       \
    }                                                                          \
    rank[i] = r + sum_rd;                                                      \
  }                                                                            \
  _Pragma("unroll")                                                            \
  for (int i = 0; i < 5; i++){                                                 \
    if (rank[i] < 0)      { rank[i] += 5; rem0[i] += 5.0f; }                   \
    else if (rank[i] > 4) { rank[i] -= 5; rem0[i] -= 5.0f; }                   \
  }                                                                            \
  float b[6] = {0.f,0.f,0.f,0.f,0.f,0.f};                                      \
  _Pragma("unroll")                                                            \
  for (int i = 0; i < 5; i++){                                                 \
    float v = (elev[i] - rem0[i]) / 5.0f;                                      \
    b[4 - rank[i]] += v;                                                       \
    b[5 - rank[i]] -= v;                                                       \
  }                                                                            \
  b[0] += 1.0f + b[5];                                                         \
  int rem0i[4];                                                                \
  _Pragma("unroll")                                                            \
  for (int i = 0; i < 4; i++) rem0i[i] = (int)rem0[i];

// Dense-path per-point result (shared by build & slice — bit-identical math).
__device__ __forceinline__ LatPt lat_compute(int n, float imgv)
{
  LATTICE_MATH(n)
  LatPt p;
  #pragma unroll
  for (int r = 0; r < 5; r++){
    int q0 = (rem0i[0] / 5) - (rank[0] < 5 - r ? 0 : 1) + GO0;
    int q1 = (rem0i[1] / 5) - (rank[1] < 5 - r ? 0 : 1) + GO1;
    int q2 = (rem0i[2] / 5) - (rank[2] < 5 - r ? 0 : 1) + GO2;
    int q3 = (rem0i[3] / 5) - (rank[3] < 5 - r ? 0 : 1) + GO3;
    int cell = (((q0 * GD1 + q1) * GD2 + q2) * GD3 + q3) * 5 + r;
    if ((unsigned)cell >= (unsigned)GCELLS) cell = GCELLS;
    p.cell[r] = cell;
    p.w[r] = b[r];
  }
  return p;
}

// Phase 1: hybrid chain-build + LDS-walk aggregation.
// MLP restructure: batched optimistic CAS (5 outstanding), batched exch,
// next-first chain walk with explicit b128 ls_q loads.
__global__ void k_build_hyb(const float* __restrict__ image,
                            const float* __restrict__ input_,
                            int* __restrict__ head,
                            int4* __restrict__ nodes)
{
  __shared__ int   ls_cell[LHS];
  __shared__ int   ls_head[LHS];
  __shared__ int   ls_next[1280];
  __shared__ float ls_w[1280];
  __shared__ float ls_q[256 * 4];     // stride 4, 16B aligned -> ds_read_b128
  __shared__ int   ls_cnt;

  int tid = threadIdx.x;
  #pragma unroll
  for (int i = 0; i < LHS / 256; i++){
    ls_cell[tid + 256 * i] = -1;
    ls_head[tid + 256 * i] = -1;
  }
  if (tid == 0) ls_cnt = 0;
  __syncthreads();

  int n = blockIdx.x * 256 + tid;
  float q0 = input_[n], q1 = input_[NPTS + n], q2 = input_[2 * NPTS + n], q3 = input_[3 * NPTS + n];
  *reinterpret_cast<float4*>(&ls_q[tid * 4]) = make_float4(q0, q1, q2, q3);
  LatPt P = lat_compute(n, image[n]);

  // Batched optimistic CAS: issue all unresolved probes each round.
  unsigned int h[5];
  #pragma unroll
  for (int r = 0; r < 5; r++)
    h[r] = ((unsigned int)P.cell[r] * 2654435761u) & (LHS - 1);

  unsigned int pend = 0x1F;
  while (pend){
    int prevs[5];
    #pragma unroll
    for (int r = 0; r < 5; r++)
      if (pend & (1u << r))
        prevs[r] = atomicCAS(&ls_cell[h[r]], -1, P.cell[r]);
    #pragma unroll
    for (int r = 0; r < 5; r++){
      if (pend & (1u << r)){
        if (prevs[r] == -1 || prevs[r] == P.cell[r]) pend &= ~(1u << r);
        else h[r] = (h[r] + 1) & (LHS - 1);
      }
    }
  }

  // Batched chain pushes (5 independent exch back-to-back).
  int e0 = tid * 5;
  #pragma unroll
  for (int r = 0; r < 5; r++) ls_w[e0 + r] = P.w[r];
  int olds[5];
  #pragma unroll
  for (int r = 0; r < 5; r++) olds[r] = atomicExch(&ls_head[h[r]], e0 + r);
  #pragma unroll
  for (int r = 0; r < 5; r++) ls_next[e0 + r] = olds[r];
  __syncthreads();

  int blockBase = blockIdx.x * 1280;
  for (int i = tid; i < LHS; i += 256){
    int cell = ls_cell[i];
    if (cell < 0) continue;
    float s0 = 0.f, s1 = 0.f, s2 = 0.f, s3 = 0.f, s4 = 0.f;
    int e = ls_head[i];
    while (e >= 0){
      int en = ls_next[e];                 // next-hop pointer issues first
      float w = ls_w[e];
      float4 q = *reinterpret_cast<const float4*>(&ls_q[(e / 5) * 4]);  // b128
      s0 += w * q.x; s1 += w * q.y; s2 += w * q.z; s3 += w * q.w; s4 += w;
      e = en;
    }
    int li = atomicAdd(&ls_cnt, 1);      // LDS counter: compact node index
    int node = blockBase + li;
    int old = atomicExch(&head[cell], node);
    __half2 h01 = __floats2half2_rn(s0, s1);
    __half2 h23 = __floats2half2_rn(s2, s3);
    int4 raw;
    raw.x = old;
    raw.y = *reinterpret_cast<int*>(&h01);
    raw.z = *reinterpret_cast<int*>(&h23);
    raw.w = __float_as_int(s4);
    nodes[node] = raw;                   // single 16B store
  }
}

// Phase 2: gather — walk pre-summed node chains (one 16B load per hop);
// write the 12B cell record; emit occupancy bitmap via wave ballot.
__global__ void k_gather_agg(const int* __restrict__ head,
                             const int4* __restrict__ nodes,
                             int3* __restrict__ vals,
                             unsigned int* __restrict__ bitmap)
{
  int c = blockIdx.x * blockDim.x + threadIdx.x;
  int e = -1;
  if (c < GCELLS1) e = head[c];
  bool occ = (e >= 0);
  unsigned long long mask = __ballot(occ);
  int lane = threadIdx.x & 63;
  if (lane == 0)       bitmap[c >> 5] = (unsigned int)(mask & 0xffffffffu);
  else if (lane == 32) bitmap[c >> 5] = (unsigned int)(mask >> 32);
  if (c >= GCELLS1) return;

  float s0 = 0.f, s1 = 0.f, s2 = 0.f, s3 = 0.f, s4 = 0.f;
  while (e >= 0){
    int4 raw = nodes[e];                 // one 16B load: next+q01+q23+w4
    __half2 h01 = *reinterpret_cast<__half2*>(&raw.y);
    __half2 h23 = *reinterpret_cast<__half2*>(&raw.z);
    float2 f01 = __half22float2(h01);
    float2 f23 = __half22float2(h23);
    s0 += f01.x; s1 += f01.y; s2 += f23.x; s3 += f23.y;
    s4 += __int_as_float(raw.w);
    e = raw.x;
  }
  __half2 o01 = __floats2half2_rn(s0, s1);
  __half2 o23 = __floats2half2_rn(s2, s3);
  int3 rec;
  rec.x = *reinterpret_cast<int*>(&o01);
  rec.y = *reinterpret_cast<int*>(&o23);
  rec.z = __float_as_int(s4);
  vals[c] = rec;
}

// Phase 3: blur pass over 12B records. Numerators fp16 (computed fp32),
// w4 fp32 exact. zfill=1 only on pass 1 (ping-pong invariant).
__global__ void k_blur_d(const unsigned int* __restrict__ bitmap,
                         const int3* __restrict__ vin,
                         int3* __restrict__ vout,
                         int dPa, int dPb, int dMa, int dMb, int zfill)
{
  int c = blockIdx.x * blockDim.x + threadIdx.x;
  if (c >= GCELLS) return;
  unsigned int w = bitmap[c >> 5];
  if (!((w >> (c & 31)) & 1u)){
    if (zfill){
      int3 zero; zero.x = 0; zero.y = 0; zero.z = 0;
      vout[c] = zero;
    }
    return;
  }
  int r = c % 5;
  int p1 = c + (r == 4 ? dPb : dPa);
  int p2 = c + (r == 0 ? dMb : dMa);
  int3 a  = vin[c];
  int3 b1 = vin[p1];   // empty neighbors hold zero records
  int3 b2 = vin[p2];

  float2 a01 = __half22float2(*reinterpret_cast<__half2*>(&a.x));
  float2 a23 = __half22float2(*reinterpret_cast<__half2*>(&a.y));
  float  aw  = __int_as_float(a.z);
  float2 m01 = __half22float2(*reinterpret_cast<__half2*>(&b1.x));
  float2 m23 = __half22float2(*reinterpret_cast<__half2*>(&b1.y));
  float  mw  = __int_as_float(b1.z);
  float2 n01 = __half22float2(*reinterpret_cast<__half2*>(&b2.x));
  float2 n23 = __half22float2(*reinterpret_cast<__half2*>(&b2.y));
  float  nw  = __int_as_float(b2.z);

  float o0 = 0.5f * a01.x + 0.25f * (m01.x + n01.x);
  float o1 = 0.5f * a01.y + 0.25f * (m01.y + n01.y);
  float o2 = 0.5f * a23.x + 0.25f * (m23.x + n23.x);
  float o3 = 0.5f * a23.y + 0.25f * (m23.y + n23.y);
  float ow = 0.5f * aw    + 0.25f * (mw    + nw);

  __half2 o01 = __floats2half2_rn(o0, o1);
  __half2 o23 = __floats2half2_rn(o2, o3);
  int3 rec;
  rec.x = *reinterpret_cast<int*>(&o01);
  rec.y = *reinterpret_cast<int*>(&o23);
  rec.z = __float_as_int(ow);
  vout[c] = rec;
}

// Phase 4: slice + normalize — recomputes cells & weights via lat_compute.
__global__ void k_slice_d(const float* __restrict__ image,
                          const int3* __restrict__ vals,
                          float* __restrict__ out)
{
  int n = blockIdx.x * blockDim.x + threadIdx.x;
  if (n >= NPTS) return;
  LatPt P = lat_compute(n, image[n]);

  float s0 = 0.f, s1 = 0.f, s2 = 0.f, s3 = 0.f, s4 = 0.f;
  #pragma unroll
  for (int r = 0; r < 5; r++){
    float w = P.w[r];
    int3 rec = vals[P.cell[r]];
    float2 f01 = __half22float2(*reinterpret_cast<__half2*>(&rec.x));
    float2 f23 = __half22float2(*reinterpret_cast<__half2*>(&rec.y));
    s0 += w * f01.x; s1 += w * f01.y; s2 += w * f23.x; s3 += w * f23.y;
    s4 += w * __int_as_float(rec.z);
  }
  float denom = s4 + 2.2204460492503131e-16f;
  out[n]            = s0 / denom;
  out[NPTS + n]     = s1 / denom;
  out[2 * NPTS + n] = s2 / denom;
  out[3 * NPTS + n] = s3 / denom;
}

// ============================ HOST ============================

extern "C" void kernel_launch(void* const* d_in, const int* in_sizes, int n_in,
                              void* d_out, int out_size, void* d_ws, size_t ws_size,
                              hipStream_t stream)
{
  const float* input_ = (const float*)d_in[0];
  const float* image  = (const float*)d_in[1];
  float* out = (float*)d_out;
  char* ws = (char*)d_ws;

  const int NB = (NPTS + 255) / 256;
  const int CB = (GCELLS1 + 255) / 256;
  const size_t BMWORDS = (size_t)CB * 8;
  const int Sj[5] = { GS0, GS1, GS2, GS3, 0 };

  // Workspace (~131 MB aliased): bitmap | head | nodes | valsA.
  // valsB ALIASED over head+nodes (14.8+70.8 MB >= 44.5 needed): both dead
  // after k_gather_agg; blur j=0 zfills valsB's empty cells.
  size_t o = 0;
  size_t off_bm   = o; o += BMWORDS * 4;              o = (o + 255) & ~(size_t)255;
  size_t off_dead = o;                                 // head+nodes region
  size_t off_head = o; o += (size_t)GCELLS1 * 4;      o = (o + 255) & ~(size_t)255;
  size_t off_node = o; o += (size_t)NP5 * 16;         o = (o + 255) & ~(size_t)255;
  size_t dead_end = o;
  size_t off_vA   = o; o += (size_t)GCELLS1 * 12;
  size_t vB_need  = (size_t)GCELLS1 * 12;
  size_t off_vB   = off_dead;
  if (dead_end - off_dead < vB_need || o > ws_size){
    // non-aliased fallback layout
    off_vB = (o + 255) & ~(size_t)255;
  }

  unsigned int* bitmap = (unsigned int*)(ws + off_bm);
  int*          head   = (int*)(ws + off_head);
  int4*         nodes  = (int4*)(ws + off_node);
  int3*         valsA  = (int3*)(ws + off_vA);
  int3*         valsB  = (int3*)(ws + off_vB);

  hipMemsetAsync(head, 0xFF, (size_t)GCELLS1 * 4, stream);

  k_build_hyb<<<NB, 256, 0, stream>>>(image, input_, head, nodes);
  k_gather_agg<<<CB, 256, 0, stream>>>(head, nodes, valsA, bitmap);

  int3* vin = valsA; int3* vout = valsB;
  for (int j = 0; j < 5; j++){
    int dPa = 1 - Sj[j];
    int dPb = GSSUM - Sj[j] - 4;
    int dMa = Sj[j] - 1;
    int dMb = Sj[j] - GSSUM + 4;
    k_blur_d<<<CB, 256, 0, stream>>>(bitmap, vin, vout, dPa, dPb, dMa, dMb,
                                     (j == 0) ? 1 : 0);
    int3* t = vin; vin = vout; vout = t;
  }

  k_slice_d<<<NB, 256, 0, stream>>>(image, vin, out);
}

// Round 15
// 183.323 us; speedup vs baseline: 1.1526x; 1.1526x over previous
//
#include <hip/hip_runtime.h>
#include <hip/hip_fp16.h>
#include <stdint.h>

#define NPTS (96*96*96)          // 884736
#define NP5  (NPTS*5)            // 4423680 entries (point,vertex)

// Dense lattice grid (interval arithmetic from fixed domain: z,y,x in [0,95],
// image in [0,1); incl. rank-adjust, r-offset, blur padding, +/-2 margin):
//   q0 in [-3,25], q1 in [-14,14], q2 in [-16,8], q3 in [-17,3]
#define GD1 33
#define GD2 29
#define GD3 25
#define GO0 5
#define GO1 16
#define GO2 18
#define GO3 19
#define GS3 5
#define GS2 (GD3*GS3)      // 125
#define GS1 (GD2*GS2)      // 3625
#define GS0 (GD1*GS1)      // 119625
#define GCELLS (31*GS0)    // 3708375
#define GCELLS1 (GCELLS+1) // + trash cell for (never-expected) OOB
#define GSSUM (GS0+GS1+GS2+GS3)  // 123380

#define LHS 2048           // block-local LDS hash slots (1280 entries -> load <=0.625)

struct LatPt { int cell[5]; float w[5]; };

// Per-cell value record: 12B = { q01:half2, q23:half2, w4:float }.
// Numerators fp16 (rounded per pass), denominator fp32 (exact). int3 access.

// Shared per-point lattice math macro producing rank[5], rem0i[4], b[]
#define LATTICE_MATH(n)                                                        \
  int x = n % 96, y = (n / 96) % 96, z = n / (96 * 96);                        \
  float cf[4];                                                                 \
  cf[0] = ((float)z / 5.0f) * 2.8867513459481287f;                             \
  cf[1] = ((float)y / 5.0f) * 1.6666666666666667f;                             \
  cf[2] = ((float)x / 5.0f) * 1.1785113019775793f;                             \
  cf[3] = (imgv / 0.25f) * 0.9128709291752769f;                                \
  float elev[5];                                                               \
  float sm = 0.f;                                                              \
  _Pragma("unroll")                                                            \
  for (int i = 4; i >= 1; --i){ float c = cf[i-1]; elev[i] = sm - (float)i * c; sm += c; } \
  elev[0] = sm;                                                                \
  float rem0[5]; float sumrd_f = 0.f;                                          \
  _Pragma("unroll")                                                            \
  for (int i = 0; i < 5; i++){ float rd = rintf(elev[i] / 5.0f); rem0[i] = rd * 5.0f; sumrd_f += rd; } \
  int sum_rd = (int)sumrd_f;                                                   \
  float diff[5];                                                               \
  _Pragma("unroll")                                                            \
  for (int i = 0; i < 5; i++) diff[i] = elev[i] - rem0[i];                     \
  int rank[5];                                                                 \
  _Pragma("unroll")                                                            \
  for (int i = 0; i < 5; i++){                                                 \
    int r = 0;                                                                 \
    _Pragma("unroll")                                                          \
    for (int j = 0; j < 5; j++){                                               \
      r += (diff[j] > diff[i] || (diff[j] == diff[i] && j < i)) ? 1 : 0;       \
    }                                                                          \
    rank[i] = r + sum_rd;                                                      \
  }                                                                            \
  _Pragma("unroll")                                                            \
  for (int i = 0; i < 5; i++){                                                 \
    if (rank[i] < 0)      { rank[i] += 5; rem0[i] += 5.0f; }                   \
    else if (rank[i] > 4) { rank[i] -= 5; rem0[i] -= 5.0f; }                   \
  }                                                                            \
  float b[6] = {0.f,0.f,0.f,0.f,0.f,0.f};                                      \
  _Pragma("unroll")                                                            \
  for (int i = 0; i < 5; i++){                                                 \
    float v = (elev[i] - rem0[i]) / 5.0f;                                      \
    b[4 - rank[i]] += v;                                                       \
    b[5 - rank[i]] -= v;                                                       \
  }                                                                            \
  b[0] += 1.0f + b[5];                                                         \
  int rem0i[4];                                                                \
  _Pragma("unroll")                                                            \
  for (int i = 0; i < 4; i++) rem0i[i] = (int)rem0[i];

// Dense-path per-point result (shared by build & slice — bit-identical math).
__device__ __forceinline__ LatPt lat_compute(int n, float imgv)
{
  LATTICE_MATH(n)
  LatPt p;
  #pragma unroll
  for (int r = 0; r < 5; r++){
    int q0 = (rem0i[0] / 5) - (rank[0] < 5 - r ? 0 : 1) + GO0;
    int q1 = (rem0i[1] / 5) - (rank[1] < 5 - r ? 0 : 1) + GO1;
    int q2 = (rem0i[2] / 5) - (rank[2] < 5 - r ? 0 : 1) + GO2;
    int q3 = (rem0i[3] / 5) - (rank[3] < 5 - r ? 0 : 1) + GO3;
    int cell = (((q0 * GD1 + q1) * GD2 + q2) * GD3 + q3) * 5 + r;
    if ((unsigned)cell >= (unsigned)GCELLS) cell = GCELLS;
    p.cell[r] = cell;
    p.w[r] = b[r];
  }
  return p;
}

// Phase 1: hybrid chain-build + LDS-walk aggregation.
// R12 sequential CAS (R13's batching regressed — reverted). NEW: CAS winners
// push their slot onto a dense list; phase 1b iterates it with ~full lane
// utilization (no 2048-slot sparse scan, no second counter pass).
__global__ void k_build_hyb(const float* __restrict__ image,
                            const float* __restrict__ input_,
                            int* __restrict__ head,
                            int4* __restrict__ nodes)
{
  __shared__ int   ls_cell[LHS];
  __shared__ int   ls_head[LHS];
  __shared__ short ls_next[1280];
  __shared__ float ls_w[1280];
  __shared__ float ls_q[256 * 4];     // stride 4, 16B aligned -> ds_read_b128
  __shared__ short ls_slot[1280];     // dense list of occupied slots
  __shared__ int   ls_cnt;

  int tid = threadIdx.x;
  #pragma unroll
  for (int i = 0; i < LHS / 256; i++){
    ls_cell[tid + 256 * i] = -1;
    ls_head[tid + 256 * i] = -1;
  }
  if (tid == 0) ls_cnt = 0;
  __syncthreads();

  int n = blockIdx.x * 256 + tid;
  float q0 = input_[n], q1 = input_[NPTS + n], q2 = input_[2 * NPTS + n], q3 = input_[3 * NPTS + n];
  *reinterpret_cast<float4*>(&ls_q[tid * 4]) = make_float4(q0, q1, q2, q3);
  LatPt P = lat_compute(n, image[n]);

  #pragma unroll
  for (int r = 0; r < 5; r++){
    int cell = P.cell[r];
    unsigned int h = ((unsigned int)cell * 2654435761u) & (LHS - 1);
    while (true){
      int prev = atomicCAS(&ls_cell[h], -1, cell);
      if (prev == -1){
        int li = atomicAdd(&ls_cnt, 1);      // winner registers the slot
        ls_slot[li] = (short)h;
        break;
      }
      if (prev == cell) break;
      h = (h + 1) & (LHS - 1);
    }
    int e = tid * 5 + r;
    ls_w[e] = P.w[r];
    ls_next[e] = (short)atomicExch(&ls_head[h], e);   // local chain push
  }
  __syncthreads();

  int cnt = ls_cnt;
  int blockBase = blockIdx.x * 1280;
  for (int i = tid; i < cnt; i += 256){
    int slot = ls_slot[i];
    int cell = ls_cell[slot];
    float s0 = 0.f, s1 = 0.f, s2 = 0.f, s3 = 0.f, s4 = 0.f;
    int e = ls_head[slot];
    while (e >= 0){
      int en = ls_next[e];                 // next-hop pointer issues first
      float w = ls_w[e];
      float4 q = *reinterpret_cast<const float4*>(&ls_q[(e / 5) * 4]);  // b128
      s0 += w * q.x; s1 += w * q.y; s2 += w * q.z; s3 += w * q.w; s4 += w;
      e = en;
    }
    int node = blockBase + i;              // dense list position = node index
    int old = atomicExch(&head[cell], node);
    __half2 h01 = __floats2half2_rn(s0, s1);
    __half2 h23 = __floats2half2_rn(s2, s3);
    int4 raw;
    raw.x = old;
    raw.y = *reinterpret_cast<int*>(&h01);
    raw.z = *reinterpret_cast<int*>(&h23);
    raw.w = __float_as_int(s4);
    nodes[node] = raw;                     // single 16B store
  }
}

// Phase 2: gather — walk pre-summed node chains (one 16B load per hop);
// write the 12B cell record; emit occupancy bitmap via wave ballot.
__global__ void k_gather_agg(const int* __restrict__ head,
                             const int4* __restrict__ nodes,
                             int3* __restrict__ vals,
                             unsigned int* __restrict__ bitmap)
{
  int c = blockIdx.x * blockDim.x + threadIdx.x;
  int e = -1;
  if (c < GCELLS1) e = head[c];
  bool occ = (e >= 0);
  unsigned long long mask = __ballot(occ);
  int lane = threadIdx.x & 63;
  if (lane == 0)       bitmap[c >> 5] = (unsigned int)(mask & 0xffffffffu);
  else if (lane == 32) bitmap[c >> 5] = (unsigned int)(mask >> 32);
  if (c >= GCELLS1) return;

  float s0 = 0.f, s1 = 0.f, s2 = 0.f, s3 = 0.f, s4 = 0.f;
  while (e >= 0){
    int4 raw = nodes[e];                 // one 16B load: next+q01+q23+w4
    __half2 h01 = *reinterpret_cast<__half2*>(&raw.y);
    __half2 h23 = *reinterpret_cast<__half2*>(&raw.z);
    float2 f01 = __half22float2(h01);
    float2 f23 = __half22float2(h23);
    s0 += f01.x; s1 += f01.y; s2 += f23.x; s3 += f23.y;
    s4 += __int_as_float(raw.w);
    e = raw.x;
  }
  __half2 o01 = __floats2half2_rn(s0, s1);
  __half2 o23 = __floats2half2_rn(s2, s3);
  int3 rec;
  rec.x = *reinterpret_cast<int*>(&o01);
  rec.y = *reinterpret_cast<int*>(&o23);
  rec.z = __float_as_int(s4);
  vals[c] = rec;
}

// Phase 3: blur pass over 12B records. Numerators fp16 (computed fp32),
// w4 fp32 exact. zfill=1 only on pass 1 (ping-pong invariant).
__global__ void k_blur_d(const unsigned int* __restrict__ bitmap,
                         const int3* __restrict__ vin,
                         int3* __restrict__ vout,
                         int dPa, int dPb, int dMa, int dMb, int zfill)
{
  int c = blockIdx.x * blockDim.x + threadIdx.x;
  if (c >= GCELLS) return;
  unsigned int w = bitmap[c >> 5];
  if (!((w >> (c & 31)) & 1u)){
    if (zfill){
      int3 zero; zero.x = 0; zero.y = 0; zero.z = 0;
      vout[c] = zero;
    }
    return;
  }
  int r = c % 5;
  int p1 = c + (r == 4 ? dPb : dPa);
  int p2 = c + (r == 0 ? dMb : dMa);
  int3 a  = vin[c];
  int3 b1 = vin[p1];   // empty neighbors hold zero records
  int3 b2 = vin[p2];

  float2 a01 = __half22float2(*reinterpret_cast<__half2*>(&a.x));
  float2 a23 = __half22float2(*reinterpret_cast<__half2*>(&a.y));
  float  aw  = __int_as_float(a.z);
  float2 m01 = __half22float2(*reinterpret_cast<__half2*>(&b1.x));
  float2 m23 = __half22float2(*reinterpret_cast<__half2*>(&b1.y));
  float  mw  = __int_as_float(b1.z);
  float2 n01 = __half22float2(*reinterpret_cast<__half2*>(&b2.x));
  float2 n23 = __half22float2(*reinterpret_cast<__half2*>(&b2.y));
  float  nw  = __int_as_float(b2.z);

  float o0 = 0.5f * a01.x + 0.25f * (m01.x + n01.x);
  float o1 = 0.5f * a01.y + 0.25f * (m01.y + n01.y);
  float o2 = 0.5f * a23.x + 0.25f * (m23.x + n23.x);
  float o3 = 0.5f * a23.y + 0.25f * (m23.y + n23.y);
  float ow = 0.5f * aw    + 0.25f * (mw    + nw);

  __half2 o01 = __floats2half2_rn(o0, o1);
  __half2 o23 = __floats2half2_rn(o2, o3);
  int3 rec;
  rec.x = *reinterpret_cast<int*>(&o01);
  rec.y = *reinterpret_cast<int*>(&o23);
  rec.z = __float_as_int(ow);
  vout[c] = rec;
}

// Phase 4: slice + normalize — recomputes cells & weights via lat_compute.
__global__ void k_slice_d(const float* __restrict__ image,
                          const int3* __restrict__ vals,
                          float* __restrict__ out)
{
  int n = blockIdx.x * blockDim.x + threadIdx.x;
  if (n >= NPTS) return;
  LatPt P = lat_compute(n, image[n]);

  float s0 = 0.f, s1 = 0.f, s2 = 0.f, s3 = 0.f, s4 = 0.f;
  #pragma unroll
  for (int r = 0; r < 5; r++){
    float w = P.w[r];
    int3 rec = vals[P.cell[r]];
    float2 f01 = __half22float2(*reinterpret_cast<__half2*>(&rec.x));
    float2 f23 = __half22float2(*reinterpret_cast<__half2*>(&rec.y));
    s0 += w * f01.x; s1 += w * f01.y; s2 += w * f23.x; s3 += w * f23.y;
    s4 += w * __int_as_float(rec.z);
  }
  float denom = s4 + 2.2204460492503131e-16f;
  out[n]            = s0 / denom;
  out[NPTS + n]     = s1 / denom;
  out[2 * NPTS + n] = s2 / denom;
  out[3 * NPTS + n] = s3 / denom;
}

// ============================ HOST ============================

extern "C" void kernel_launch(void* const* d_in, const int* in_sizes, int n_in,
                              void* d_out, int out_size, void* d_ws, size_t ws_size,
                              hipStream_t stream)
{
  const float* input_ = (const float*)d_in[0];
  const float* image  = (const float*)d_in[1];
  float* out = (float*)d_out;
  char* ws = (char*)d_ws;

  const int NB = (NPTS + 255) / 256;
  const int CB = (GCELLS1 + 255) / 256;
  const size_t BMWORDS = (size_t)CB * 8;
  const int Sj[5] = { GS0, GS1, GS2, GS3, 0 };

  // Workspace (~131 MB aliased): bitmap | head | nodes | valsA.
  // valsB ALIASED over head+nodes (14.8+70.8 MB >= 44.5 needed): both dead
  // after k_gather_agg; blur j=0 zfills valsB's empty cells.
  size_t o = 0;
  size_t off_bm   = o; o += BMWORDS * 4;              o = (o + 255) & ~(size_t)255;
  size_t off_dead = o;                                 // head+nodes region
  size_t off_head = o; o += (size_t)GCELLS1 * 4;      o = (o + 255) & ~(size_t)255;
  size_t off_node = o; o += (size_t)NP5 * 16;         o = (o + 255) & ~(size_t)255;
  size_t dead_end = o;
  size_t off_vA   = o; o += (size_t)GCELLS1 * 12;
  size_t vB_need  = (size_t)GCELLS1 * 12;
  size_t off_vB   = off_dead;
  if (dead_end - off_dead < vB_need || o > ws_size){
    // non-aliased fallback layout
    off_vB = (o + 255) & ~(size_t)255;
  }

  unsigned int* bitmap = (unsigned int*)(ws + off_bm);
  int*          head   = (int*)(ws + off_head);
  int4*         nodes  = (int4*)(ws + off_node);
  int3*         valsA  = (int3*)(ws + off_vA);
  int3*         valsB  = (int3*)(ws + off_vB);

  hipMemsetAsync(head, 0xFF, (size_t)GCELLS1 * 4, stream);

  k_build_hyb<<<NB, 256, 0, stream>>>(image, input_, head, nodes);
  k_gather_agg<<<CB, 256, 0, stream>>>(head, nodes, valsA, bitmap);

  int3* vin = valsA; int3* vout = valsB;
  for (int j = 0; j < 5; j++){
    int dPa = 1 - Sj[j];
    int dPb = GSSUM - Sj[j] - 4;
    int dMa = Sj[j] - 1;
    int dMb = Sj[j] - GSSUM + 4;
    k_blur_d<<<CB, 256, 0, stream>>>(bitmap, vin, vout, dPa, dPb, dMa, dMb,
                                     (j == 0) ? 1 : 0);
    int3* t = vin; vin = vout; vout = t;
  }

  k_slice_d<<<NB, 256, 0, stream>>>(image, vin, out);
}

// Round 16
// 175.337 us; speedup vs baseline: 1.2051x; 1.0456x over previous
//
#include <hip/hip_runtime.h>
#include <hip/hip_fp16.h>
#include <stdint.h>

#define NPTS (96*96*96)          // 884736
#define NP5  (NPTS*5)            // 4423680 entries (point,vertex)

// Dense lattice grid (interval arithmetic from fixed domain: z,y,x in [0,95],
// image in [0,1); incl. rank-adjust, r-offset, blur padding, +/-2 margin):
//   q0 in [-3,25], q1 in [-14,14], q2 in [-16,8], q3 in [-17,3]
#define GD1 33
#define GD2 29
#define GD3 25
#define GO0 5
#define GO1 16
#define GO2 18
#define GO3 19
#define GS3 5
#define GS2 (GD3*GS3)      // 125
#define GS1 (GD2*GS2)      // 3625
#define GS0 (GD1*GS1)      // 119625
#define GCELLS (31*GS0)    // 3708375
#define GCELLS1 (GCELLS+1) // + trash cell for (never-expected) OOB
#define GSSUM (GS0+GS1+GS2+GS3)  // 123380

#define LHS 2048           // block-local LDS hash slots (1280 entries -> load <=0.625)

struct LatPt { int cell[5]; float w[5]; };
struct V5 { float s0, s1, s2, s3, w; };

// Per-cell value record: 12B = { q01:half2, q23:half2, w4:float }.
// Numerators fp16 (rounded per pass), denominator fp32 (exact). int3 access.

// Shared per-point lattice math macro producing rank[5], rem0i[4], b[]
#define LATTICE_MATH(n)                                                        \
  int x = n % 96, y = (n / 96) % 96, z = n / (96 * 96);                        \
  float cf[4];                                                                 \
  cf[0] = ((float)z / 5.0f) * 2.8867513459481287f;                             \
  cf[1] = ((float)y / 5.0f) * 1.6666666666666667f;                             \
  cf[2] = ((float)x / 5.0f) * 1.1785113019775793f;                             \
  cf[3] = (imgv / 0.25f) * 0.9128709291752769f;                                \
  float elev[5];                                                               \
  float sm = 0.f;                                                              \
  _Pragma("unroll")                                                            \
  for (int i = 4; i >= 1; --i){ float c = cf[i-1]; elev[i] = sm - (float)i * c; sm += c; } \
  elev[0] = sm;                                                                \
  float rem0[5]; float sumrd_f = 0.f;                                          \
  _Pragma("unroll")                                                            \
  for (int i = 0; i < 5; i++){ float rd = rintf(elev[i] / 5.0f); rem0[i] = rd * 5.0f; sumrd_f += rd; } \
  int sum_rd = (int)sumrd_f;                                                   \
  float diff[5];                                                               \
  _Pragma("unroll")                                                            \
  for (int i = 0; i < 5; i++) diff[i] = elev[i] - rem0[i];                     \
  int rank[5];                                                                 \
  _Pragma("unroll")                                                            \
  for (int i = 0; i < 5; i++){                                                 \
    int r = 0;                                                                 \
    _Pragma("unroll")                                                          \
    for (int j = 0; j < 5; j++){                                               \
      r += (diff[j] > diff[i] || (diff[j] == diff[i] && j < i)) ? 1 : 0;       \
    }                                                                          \
    rank[i] = r + sum_rd;                                                      \
  }                                                                            \
  _Pragma("unroll")                                                            \
  for (int i = 0; i < 5; i++){                                                 \
    if (rank[i] < 0)      { rank[i] += 5; rem0[i] += 5.0f; }                   \
    else if (rank[i] > 4) { rank[i] -= 5; rem0[i] -= 5.0f; }                   \
  }                                                                            \
  float b[6] = {0.f,0.f,0.f,0.f,0.f,0.f};                                      \
  _Pragma("unroll")                                                            \
  for (int i = 0; i < 5; i++){                                                 \
    float v = (elev[i] - rem0[i]) / 5.0f;                                      \
    b[4 - rank[i]] += v;                                                       \
    b[5 - rank[i]] -= v;                                                       \
  }                                                                            \
  b[0] += 1.0f + b[5];                                                         \
  int rem0i[4];                                                                \
  _Pragma("unroll")                                                            \
  for (int i = 0; i < 4; i++) rem0i[i] = (int)rem0[i];

// Dense-path per-point result (shared by build & slice — bit-identical math).
__device__ __forceinline__ LatPt lat_compute(int n, float imgv)
{
  LATTICE_MATH(n)
  LatPt p;
  #pragma unroll
  for (int r = 0; r < 5; r++){
    int q0 = (rem0i[0] / 5) - (rank[0] < 5 - r ? 0 : 1) + GO0;
    int q1 = (rem0i[1] / 5) - (rank[1] < 5 - r ? 0 : 1) + GO1;
    int q2 = (rem0i[2] / 5) - (rank[2] < 5 - r ? 0 : 1) + GO2;
    int q3 = (rem0i[3] / 5) - (rank[3] < 5 - r ? 0 : 1) + GO3;
    int cell = (((q0 * GD1 + q1) * GD2 + q2) * GD3 + q3) * 5 + r;
    if ((unsigned)cell >= (unsigned)GCELLS) cell = GCELLS;
    p.cell[r] = cell;
    p.w[r] = b[r];
  }
  return p;
}

// Phase 1: hybrid chain-build + LDS-walk aggregation (R14 structure, unchanged).
__global__ void k_build_hyb(const float* __restrict__ image,
                            const float* __restrict__ input_,
                            int* __restrict__ head,
                            int4* __restrict__ nodes)
{
  __shared__ int   ls_cell[LHS];
  __shared__ int   ls_head[LHS];
  __shared__ short ls_next[1280];
  __shared__ float ls_w[1280];
  __shared__ float ls_q[256 * 4];     // stride 4, 16B aligned -> ds_read_b128
  __shared__ short ls_slot[1280];     // dense list of occupied slots
  __shared__ int   ls_cnt;

  int tid = threadIdx.x;
  #pragma unroll
  for (int i = 0; i < LHS / 256; i++){
    ls_cell[tid + 256 * i] = -1;
    ls_head[tid + 256 * i] = -1;
  }
  if (tid == 0) ls_cnt = 0;
  __syncthreads();

  int n = blockIdx.x * 256 + tid;
  float q0 = input_[n], q1 = input_[NPTS + n], q2 = input_[2 * NPTS + n], q3 = input_[3 * NPTS + n];
  *reinterpret_cast<float4*>(&ls_q[tid * 4]) = make_float4(q0, q1, q2, q3);
  LatPt P = lat_compute(n, image[n]);

  #pragma unroll
  for (int r = 0; r < 5; r++){
    int cell = P.cell[r];
    unsigned int h = ((unsigned int)cell * 2654435761u) & (LHS - 1);
    while (true){
      int prev = atomicCAS(&ls_cell[h], -1, cell);
      if (prev == -1){
        int li = atomicAdd(&ls_cnt, 1);      // winner registers the slot
        ls_slot[li] = (short)h;
        break;
      }
      if (prev == cell) break;
      h = (h + 1) & (LHS - 1);
    }
    int e = tid * 5 + r;
    ls_w[e] = P.w[r];
    ls_next[e] = (short)atomicExch(&ls_head[h], e);   // local chain push
  }
  __syncthreads();

  int cnt = ls_cnt;
  int blockBase = blockIdx.x * 1280;
  for (int i = tid; i < cnt; i += 256){
    int slot = ls_slot[i];
    int cell = ls_cell[slot];
    float s0 = 0.f, s1 = 0.f, s2 = 0.f, s3 = 0.f, s4 = 0.f;
    int e = ls_head[slot];
    while (e >= 0){
      int en = ls_next[e];                 // next-hop pointer issues first
      float w = ls_w[e];
      float4 q = *reinterpret_cast<const float4*>(&ls_q[(e / 5) * 4]);  // b128
      s0 += w * q.x; s1 += w * q.y; s2 += w * q.z; s3 += w * q.w; s4 += w;
      e = en;
    }
    int node = blockBase + i;              // dense list position = node index
    int old = atomicExch(&head[cell], node);
    __half2 h01 = __floats2half2_rn(s0, s1);
    __half2 h23 = __floats2half2_rn(s2, s3);
    int4 raw;
    raw.x = old;
    raw.y = *reinterpret_cast<int*>(&h01);
    raw.z = *reinterpret_cast<int*>(&h23);
    raw.w = __float_as_int(s4);
    nodes[node] = raw;                     // single 16B store
  }
}

// Phase 2: gather — walk pre-summed node chains (one 16B load per hop);
// write the 12B cell record; emit occupancy bitmap via wave ballot.
__global__ void k_gather_agg(const int* __restrict__ head,
                             const int4* __restrict__ nodes,
                             int3* __restrict__ vals,
                             unsigned int* __restrict__ bitmap)
{
  int c = blockIdx.x * blockDim.x + threadIdx.x;
  int e = -1;
  if (c < GCELLS1) e = head[c];
  bool occ = (e >= 0);
  unsigned long long mask = __ballot(occ);
  int lane = threadIdx.x & 63;
  if (lane == 0)       bitmap[c >> 5] = (unsigned int)(mask & 0xffffffffu);
  else if (lane == 32) bitmap[c >> 5] = (unsigned int)(mask >> 32);
  if (c >= GCELLS1) return;

  float s0 = 0.f, s1 = 0.f, s2 = 0.f, s3 = 0.f, s4 = 0.f;
  while (e >= 0){
    int4 raw = nodes[e];                 // one 16B load: next+q01+q23+w4
    __half2 h01 = *reinterpret_cast<__half2*>(&raw.y);
    __half2 h23 = *reinterpret_cast<__half2*>(&raw.z);
    float2 f01 = __half22float2(h01);
    float2 f23 = __half22float2(h23);
    s0 += f01.x; s1 += f01.y; s2 += f23.x; s3 += f23.y;
    s4 += __int_as_float(raw.w);
    e = raw.x;
  }
  __half2 o01 = __floats2half2_rn(s0, s1);
  __half2 o23 = __floats2half2_rn(s2, s3);
  int3 rec;
  rec.x = *reinterpret_cast<int*>(&o01);
  rec.y = *reinterpret_cast<int*>(&o23);
  rec.z = __float_as_int(s4);
  vals[c] = rec;
}

// Decode + 3-point stencil of direction (dPa,dPb,dMa,dMb) at cell d.
// Returns 0-vector if d unoccupied (vin zero-invariant covers neighbors).
__device__ __forceinline__ V5 ublur(const unsigned int* __restrict__ bitmap,
                                    const int3* __restrict__ vin,
                                    int d, int dPa, int dPb, int dMa, int dMb)
{
  V5 u = {0.f, 0.f, 0.f, 0.f, 0.f};
  unsigned int wd = bitmap[d >> 5];
  if (!((wd >> (d & 31)) & 1u)) return u;
  int rd = d % 5;
  int p1 = d + (rd == 4 ? dPb : dPa);
  int p2 = d + (rd == 0 ? dMb : dMa);
  int3 a  = vin[d];
  int3 b1 = vin[p1];
  int3 b2 = vin[p2];
  float2 a01 = __half22float2(*reinterpret_cast<__half2*>(&a.x));
  float2 a23 = __half22float2(*reinterpret_cast<__half2*>(&a.y));
  float2 m01 = __half22float2(*reinterpret_cast<__half2*>(&b1.x));
  float2 m23 = __half22float2(*reinterpret_cast<__half2*>(&b1.y));
  float2 n01 = __half22float2(*reinterpret_cast<__half2*>(&b2.x));
  float2 n23 = __half22float2(*reinterpret_cast<__half2*>(&b2.y));
  u.s0 = 0.5f * a01.x + 0.25f * (m01.x + n01.x);
  u.s1 = 0.5f * a01.y + 0.25f * (m01.y + n01.y);
  u.s2 = 0.5f * a23.x + 0.25f * (m23.x + n23.x);
  u.s3 = 0.5f * a23.y + 0.25f * (m23.y + n23.y);
  u.w  = 0.5f * __int_as_float(a.z) + 0.25f * (__int_as_float(b1.z) + __int_as_float(b2.z));
  return u;
}

// Phase 3a: FUSED pair of blur directions: vout = blurB(blurA(vin)).
// <=9 reads + 1 write per occupied cell vs 6 reads + 2 writes + intermediate
// round-trip for two separate passes (both vals buffers are L3-resident, so
// time scales with bytes moved). zfill only when target holds stale bytes.
__global__ void k_blur2_d(const unsigned int* __restrict__ bitmap,
                          const int3* __restrict__ vin,
                          int3* __restrict__ vout,
                          int dPaA, int dPbA, int dMaA, int dMbA,
                          int dPaB, int dPbB, int dMaB, int dMbB, int zfill)
{
  int c = blockIdx.x * blockDim.x + threadIdx.x;
  if (c >= GCELLS) return;
  unsigned int w = bitmap[c >> 5];
  if (!((w >> (c & 31)) & 1u)){
    if (zfill){
      int3 zero; zero.x = 0; zero.y = 0; zero.z = 0;
      vout[c] = zero;
    }
    return;
  }
  int r = c % 5;
  int q1 = c + (r == 4 ? dPbB : dPaB);
  int q2 = c + (r == 0 ? dMbB : dMaB);

  V5 uc = ublur(bitmap, vin, c,  dPaA, dPbA, dMaA, dMbA);
  V5 u1 = ublur(bitmap, vin, q1, dPaA, dPbA, dMaA, dMbA);
  V5 u2 = ublur(bitmap, vin, q2, dPaA, dPbA, dMaA, dMbA);

  float o0 = 0.5f * uc.s0 + 0.25f * (u1.s0 + u2.s0);
  float o1 = 0.5f * uc.s1 + 0.25f * (u1.s1 + u2.s1);
  float o2 = 0.5f * uc.s2 + 0.25f * (u1.s2 + u2.s2);
  float o3 = 0.5f * uc.s3 + 0.25f * (u1.s3 + u2.s3);
  float ow = 0.5f * uc.w  + 0.25f * (u1.w  + u2.w);

  __half2 o01 = __floats2half2_rn(o0, o1);
  __half2 o23 = __floats2half2_rn(o2, o3);
  int3 rec;
  rec.x = *reinterpret_cast<int*>(&o01);
  rec.y = *reinterpret_cast<int*>(&o23);
  rec.z = __float_as_int(ow);
  vout[c] = rec;
}

// Phase 3b: single blur pass (direction j=4). zfill=0 (target pre-zeroed).
__global__ void k_blur_d(const unsigned int* __restrict__ bitmap,
                         const int3* __restrict__ vin,
                         int3* __restrict__ vout,
                         int dPa, int dPb, int dMa, int dMb, int zfill)
{
  int c = blockIdx.x * blockDim.x + threadIdx.x;
  if (c >= GCELLS) return;
  unsigned int w = bitmap[c >> 5];
  if (!((w >> (c & 31)) & 1u)){
    if (zfill){
      int3 zero; zero.x = 0; zero.y = 0; zero.z = 0;
      vout[c] = zero;
    }
    return;
  }
  V5 u = ublur(bitmap, vin, c, dPa, dPb, dMa, dMb);
  __half2 o01 = __floats2half2_rn(u.s0, u.s1);
  __half2 o23 = __floats2half2_rn(u.s2, u.s3);
  int3 rec;
  rec.x = *reinterpret_cast<int*>(&o01);
  rec.y = *reinterpret_cast<int*>(&o23);
  rec.z = __float_as_int(u.w);
  vout[c] = rec;
}

// Phase 4: slice + normalize — recomputes cells & weights via lat_compute.
__global__ void k_slice_d(const float* __restrict__ image,
                          const int3* __restrict__ vals,
                          float* __restrict__ out)
{
  int n = blockIdx.x * blockDim.x + threadIdx.x;
  if (n >= NPTS) return;
  LatPt P = lat_compute(n, image[n]);

  float s0 = 0.f, s1 = 0.f, s2 = 0.f, s3 = 0.f, s4 = 0.f;
  #pragma unroll
  for (int r = 0; r < 5; r++){
    float w = P.w[r];
    int3 rec = vals[P.cell[r]];
    float2 f01 = __half22float2(*reinterpret_cast<__half2*>(&rec.x));
    float2 f23 = __half22float2(*reinterpret_cast<__half2*>(&rec.y));
    s0 += w * f01.x; s1 += w * f01.y; s2 += w * f23.x; s3 += w * f23.y;
    s4 += w * __int_as_float(rec.z);
  }
  float denom = s4 + 2.2204460492503131e-16f;
  out[n]            = s0 / denom;
  out[NPTS + n]     = s1 / denom;
  out[2 * NPTS + n] = s2 / denom;
  out[3 * NPTS + n] = s3 / denom;
}

// ============================ HOST ============================

extern "C" void kernel_launch(void* const* d_in, const int* in_sizes, int n_in,
                              void* d_out, int out_size, void* d_ws, size_t ws_size,
                              hipStream_t stream)
{
  const float* input_ = (const float*)d_in[0];
  const float* image  = (const float*)d_in[1];
  float* out = (float*)d_out;
  char* ws = (char*)d_ws;

  const int NB = (NPTS + 255) / 256;
  const int CB = (GCELLS1 + 255) / 256;
  const size_t BMWORDS = (size_t)CB * 8;
  const int Sj[5] = { GS0, GS1, GS2, GS3, 0 };
  int dPa[5], dPb[5], dMa[5], dMb[5];
  for (int j = 0; j < 5; j++){
    dPa[j] = 1 - Sj[j];
    dPb[j] = GSSUM - Sj[j] - 4;
    dMa[j] = Sj[j] - 1;
    dMb[j] = Sj[j] - GSSUM + 4;
  }

  // Workspace (~131 MB aliased): bitmap | head | nodes | valsA.
  // valsB ALIASED over head+nodes: both dead after k_gather_agg; the first
  // fused blur (zfill=1) zeroes valsB's empty cells over the stale bytes.
  size_t o = 0;
  size_t off_bm   = o; o += BMWORDS * 4;              o = (o + 255) & ~(size_t)255;
  size_t off_dead = o;                                 // head+nodes region
  size_t off_head = o; o += (size_t)GCELLS1 * 4;      o = (o + 255) & ~(size_t)255;
  size_t off_node = o; o += (size_t)NP5 * 16;         o = (o + 255) & ~(size_t)255;
  size_t dead_end = o;
  size_t off_vA   = o; o += (size_t)GCELLS1 * 12;
  size_t vB_need  = (size_t)GCELLS1 * 12;
  size_t off_vB   = off_dead;
  if (dead_end - off_dead < vB_need || o > ws_size){
    // non-aliased fallback layout
    off_vB = (o + 255) & ~(size_t)255;
  }

  unsigned int* bitmap = (unsigned int*)(ws + off_bm);
  int*          head   = (int*)(ws + off_head);
  int4*         nodes  = (int4*)(ws + off_node);
  int3*         valsA  = (int3*)(ws + off_vA);
  int3*         valsB  = (int3*)(ws + off_vB);

  hipMemsetAsync(head, 0xFF, (size_t)GCELLS1 * 4, stream);

  k_build_hyb<<<NB, 256, 0, stream>>>(image, input_, head, nodes);
  k_gather_agg<<<CB, 256, 0, stream>>>(head, nodes, valsA, bitmap);

  // Fused j=0+1: A -> B (zfill: B overlays stale node bytes)
  k_blur2_d<<<CB, 256, 0, stream>>>(bitmap, valsA, valsB,
                                    dPa[0], dPb[0], dMa[0], dMb[0],
                                    dPa[1], dPb[1], dMa[1], dMb[1], 1);
  // Fused j=2+3: B -> A (A's empties already zeroed by gather)
  k_blur2_d<<<CB, 256, 0, stream>>>(bitmap, valsB, valsA,
                                    dPa[2], dPb[2], dMa[2], dMb[2],
                                    dPa[3], dPb[3], dMa[3], dMb[3], 0);
  // Single j=4: A -> B (B's empties zeroed by the first fused pass)
  k_blur_d<<<CB, 256, 0, stream>>>(bitmap, valsA, valsB,
                                   dPa[4], dPb[4], dMa[4], dMb[4], 0);

  k_slice_d<<<NB, 256, 0, stream>>>(image, valsB, out);
}